// Round 18
// baseline (1225.182 us; speedup 1.0000x reference)
//
#include <hip/hip_runtime.h>

using bf16   = __bf16;
using bf16x8 = __bf16 __attribute__((ext_vector_type(8)));
using f32x4  = float  __attribute__((ext_vector_type(4)));
using i32x4  = int    __attribute__((ext_vector_type(4)));

// B=1024, T=64, F=256, H=1024, C=2
// ws layout: identical to R17 (parity XRs/Dbfs, i8 WcH3/hb, bf16 hf, Gi planes)

__device__ __forceinline__ float sigm(float x) { return 1.f / (1.f + __expf(-x)); }
__device__ __forceinline__ float tanh_fast(float x) {
  float e = __expf(2.f * x);
  return 1.f - 2.f / (e + 1.f);
}

#define GLL16(gsrc, ldst)                                                              \
  __builtin_amdgcn_global_load_lds((const __attribute__((address_space(1))) void*)(gsrc), \
                                   (__attribute__((address_space(3))) void*)(ldst), 16, 0, 0)

// ---------------------------------------------------------------------------
// prep math (shared)
// ---------------------------------------------------------------------------
__device__ __forceinline__ void prep_one(int i, int c,
    const float* __restrict__ X, const float* __restrict__ Msk,
    const float* __restrict__ D, const float* __restrict__ Mean,
    const float* __restrict__ L, const float* __restrict__ w_gx,
    const float* __restrict__ b_gx, bf16* __restrict__ XRs, bf16* __restrict__ Dbfs) {
  int f = i & 255, b = (i >> 8) & 1023, tl = i >> 18;
  int t = c * 16 + tl;
  size_t g = ((size_t)b << 14) + ((size_t)t << 8) + f;
  float d = D[g];
  int fs = f ^ ((b & 7) << 3);
  int row = tl * 1024 + b;
  Dbfs[(size_t)row * 256 + fs] = (bf16)d;
  float gx = __expf(-fmaxf(d * w_gx[f] + b_gx[f], 0.f));
  float xh = gx * L[g] + (1.f - gx) * Mean[(size_t)b * 256 + f];
  float m  = Msk[g];
  float xr = m * X[g] + (1.f - m) * xh;
  if (tl < 16) {
    size_t xo = (size_t)row * 512;
    XRs[xo + fs]       = (bf16)xr;
    XRs[xo + 256 + fs] = (bf16)m;
  }
}

__global__ void prep_kernel(const float* __restrict__ X, const float* __restrict__ Msk,
                            const float* __restrict__ D, const float* __restrict__ Mean,
                            const float* __restrict__ L, const float* __restrict__ w_gx,
                            const float* __restrict__ b_gx,
                            bf16* __restrict__ XRs, bf16* __restrict__ Dbfs,
                            int c, int nsl) {
  int i = blockIdx.x * 256 + threadIdx.x;
  if (i >= (nsl << 18)) return;
  prep_one(i, c, X, Msk, D, Mean, L, w_gx, b_gx, XRs, Dbfs);
}

// ---------------------------------------------------------------------------
// wprep: WcH3 i8 with per-gate scales (unchanged)
// ---------------------------------------------------------------------------
__global__ void wprep_kernel(const float* __restrict__ w_ih, const float* __restrict__ w_hh,
                             const float* __restrict__ b_ih, const float* __restrict__ b_hh,
                             const float* __restrict__ w_gh,
                             char* __restrict__ WcH3, bf16* __restrict__ WcX3,
                             bf16* __restrict__ Wgs, float* __restrict__ bias4) {
  int i = blockIdx.x * 256 + threadIdx.x;
  if (i < 4194304) {                       // WcH3 i8: [nb32][kt8][nl128][cc8][e16]
    int nb = i >> 17;
    int rem = i & 131071;
    int kt = rem >> 14;
    int r2 = rem & 16383;
    int nl = r2 >> 7, bb = r2 & 127;
    int cc = bb >> 4, e = bb & 15;
    int gg = nl >> 5, j = nb * 32 + (nl & 31);
    int k = kt * 128 + ((cc ^ (nl & 7)) << 4) + e;
    float v;
    if (gg == 3) v = w_hh[(size_t)(2048 + j) * 1024 + k];
    else {
      int rr = gg * 1024 + j;
      v = w_ih[(size_t)rr * 1536 + 256 + k];
      if (gg < 2) v += w_hh[(size_t)rr * 1024 + k];
    }
    float sc = (gg >= 2) ? 4096.f : 2048.f;
    int wq = __float2int_rn(v * sc);
    wq = wq > 127 ? 127 : (wq < -127 ? -127 : wq);
    WcH3[i] = (char)wq;
  } else if (i < 5767168) {                // WcX3: [nb24][kt8][nl128][c8][e8], n=g*1024+j
    int q = i - 4194304;
    int blk = q >> 13;
    int nb = blk >> 3, kt = blk & 7;
    int r = q & 8191;
    int nl = r >> 6, cc = (r >> 3) & 7, e = r & 7;
    int gg = nb >> 3;                       // 0..2
    int j  = (nb & 7) * 128 + nl;
    int rr = gg * 1024 + j;
    int k = kt * 64 + ((cc ^ (nl & 7)) << 3) + e;
    float v = (k < 256) ? w_ih[(size_t)rr * 1536 + k]
                        : w_ih[(size_t)rr * 1536 + 1280 + (k - 256)];
    WcX3[q] = (bf16)v;
  } else if (i < 6029312) {                // Wgs
    int q = i - 5767168;
    int blk = q >> 13;
    int nb = blk >> 2, kt = blk & 3;
    int r = q & 8191;
    int nl = r >> 6, cc = (r >> 3) & 7, e = r & 7;
    int n = nb * 128 + nl;
    int k = kt * 64 + ((cc ^ (nl & 7)) << 3) + e;
    Wgs[q] = (bf16)w_gh[(size_t)n * 256 + k];
  } else if (i < 6033408) {                // bias4
    int q = i - 6029312;
    int gg = q >> 10, j = q & 1023;
    float v;
    if (gg == 0)      v = b_ih[j] + b_hh[j];
    else if (gg == 1) v = b_ih[1024 + j] + b_hh[1024 + j];
    else if (gg == 2) v = b_ih[2048 + j];
    else              v = b_hh[2048 + j];
    bias4[q] = v;
  }
}

// ---------------------------------------------------------------------------
// combo: roles interleaved in dispatch order — bid%5==4 (first pp) = prep;
// others compact to oidx: [0,gx) gix, [gx,gx+gm) gammah.
// ---------------------------------------------------------------------------
__global__ __launch_bounds__(256) void combo_kernel(
    const bf16* __restrict__ XRs, const bf16* __restrict__ WcX3,
    bf16* __restrict__ Gi, int gxblocks,
    const bf16* __restrict__ Dbfs, const bf16* __restrict__ Wgs,
    const float* __restrict__ b_gh, bf16* __restrict__ GH, int gmblocks,
    const float* __restrict__ X, const float* __restrict__ Msk,
    const float* __restrict__ D, const float* __restrict__ Mean,
    const float* __restrict__ L, const float* __restrict__ w_gx,
    const float* __restrict__ b_gx,
    bf16* __restrict__ XRsN, bf16* __restrict__ DbfsN, int pc, int npsl, int pp) {
  __shared__ char smem[65536];
  char* As = smem;
  char* Bs = smem + 32768;
  int bid = blockIdx.x;
  int tid = threadIdx.x, lane = tid & 63, wid = tid >> 6;
  int wr = wid >> 1, wc = wid & 1;

  int q5 = bid / 5, r5 = bid - q5 * 5;
  if (r5 == 4 && q5 < pp) {
    // ------------------------- prep role (chunk pc) -------------------------
    int total = npsl << 18;
    for (int i = q5 * 256 + tid; i < total; i += pp * 256)
      prep_one(i, pc, X, Msk, D, Mean, L, w_gx, b_gx, XRsN, DbfsN);
    return;
  }
  int oidx = bid - ((q5 < pp) ? q5 : pp);

  if (oidx < gxblocks) {
    // ------------------------- gix role -------------------------
    int cpx = gxblocks >> 3;
    int wg = (oidx & 7) * cpx + (oidx >> 3);
    int nb = wg % 24, mb = wg / 24;

    const bf16* aA = XRs + ((size_t)(mb * 128 + wid * 8 + (lane >> 3))) * 512 + (lane & 7) * 8;
    const bf16* aB = WcX3 + (size_t)nb * 8 * 8192 + wid * 512 + lane * 8;

    f32x4 acc[4][4];
#pragma unroll
    for (int a = 0; a < 4; ++a)
#pragma unroll
      for (int b = 0; b < 4; ++b)
#pragma unroll
        for (int q = 0; q < 4; ++q) acc[a][b][q] = 0.f;

#define GX_STAGE(buf, kt)                                                         \
  do {                                                                            \
    _Pragma("unroll")                                                             \
    for (int q = 0; q < 4; ++q)                                                   \
      GLL16(aA + q * (32 * 512) + (kt) * 64, As + (buf) * 16384 + (q * 4 + wid) * 1024); \
    _Pragma("unroll")                                                             \
    for (int q = 0; q < 4; ++q)                                                   \
      GLL16(aB + (size_t)(kt) * 8192 + q * 2048, Bs + (buf) * 16384 + (q * 4 + wid) * 1024); \
  } while (0)

    GX_STAGE(0, 0);
    __syncthreads();
    for (int kt = 0; kt < 8; ++kt) {
      const int cur = kt & 1;
      if (kt < 7) GX_STAGE(cur ^ 1, kt + 1);
#pragma unroll
      for (int kk = 0; kk < 2; ++kk) {
        int kb = kk * 64 + ((lane >> 4) << 4);
        bf16x8 af[4], bfr[4];
#pragma unroll
        for (int mf = 0; mf < 4; ++mf) {
          int row = wr * 64 + mf * 16 + (lane & 15);
          af[mf] = *(const bf16x8*)(As + cur * 16384 + (((row * 128 + kb)) ^ ((row & 7) << 4)));
        }
#pragma unroll
        for (int nf = 0; nf < 4; ++nf) {
          int nl = wc * 64 + nf * 16 + (lane & 15);
          bfr[nf] = *(const bf16x8*)(Bs + cur * 16384 + (((nl * 128 + kb)) ^ ((nl & 7) << 4)));
        }
#pragma unroll
        for (int mf = 0; mf < 4; ++mf)
#pragma unroll
          for (int nf = 0; nf < 4; ++nf)
            acc[mf][nf] = __builtin_amdgcn_mfma_f32_16x16x32_bf16(af[mf], bfr[nf], acc[mf][nf], 0, 0, 0);
      }
      __syncthreads();
    }
    char* ep = smem;
#pragma unroll
    for (int nf = 0; nf < 4; ++nf) {
      int col = wc * 64 + nf * 16 + (lane & 15);
#pragma unroll
      for (int mf = 0; mf < 4; ++mf)
#pragma unroll
        for (int reg = 0; reg < 4; ++reg) {
          int row = wr * 64 + mf * 16 + ((lane >> 4) << 2) + reg;
          int cph = ((col >> 3) ^ (((row >> 2) & 3) << 2));
          *(bf16*)(ep + row * 256 + (cph << 4) + (col & 7) * 2) = (bf16)acc[mf][nf][reg];
        }
    }
    __syncthreads();
    {
      int sl = mb >> 3, mbl = mb & 7;
      bf16* plane = Gi + (size_t)sl * 3145728 + (size_t)(nb >> 3) * 1048576 + (nb & 7) * 128;
#pragma unroll
      for (int p = 0; p < 8; ++p) {
        int idx = p * 256 + tid;
        int row = idx >> 4, c = idx & 15;
        int cph = c ^ (((row >> 2) & 3) << 2);
        bf16x8 v = *(const bf16x8*)(ep + row * 256 + (cph << 4));
        __builtin_nontemporal_store(v, (bf16x8*)(plane + (size_t)(mbl * 128 + row) * 1024 + c * 8));
      }
    }
    return;
  }

  // ------------------------- gammah role -------------------------
  {
    int lbid = oidx - gxblocks;
    int cpx = gmblocks >> 3;
    int wg = (lbid & 7) * cpx + (lbid >> 3);
    int nb = wg & 7, mb = wg >> 3;

    const bf16* aA = Dbfs + ((size_t)(mb * 128 + wid * 8 + (lane >> 3))) * 256 + (lane & 7) * 8;
    const bf16* aB = Wgs + (size_t)nb * 4 * 8192 + wid * 512 + lane * 8;

    f32x4 acc[4][4];
#pragma unroll
    for (int a = 0; a < 4; ++a)
#pragma unroll
      for (int b = 0; b < 4; ++b)
#pragma unroll
        for (int q = 0; q < 4; ++q) acc[a][b][q] = 0.f;

#define GM_STAGE(buf, kt)                                                         \
  do {                                                                            \
    _Pragma("unroll")                                                             \
    for (int q = 0; q < 4; ++q)                                                   \
      GLL16(aA + q * (32 * 256) + (kt) * 64, As + (buf) * 16384 + (q * 4 + wid) * 1024); \
    _Pragma("unroll")                                                             \
    for (int q = 0; q < 4; ++q)                                                   \
      GLL16(aB + (size_t)(kt) * 8192 + q * 2048, Bs + (buf) * 16384 + (q * 4 + wid) * 1024); \
  } while (0)

    GM_STAGE(0, 0);
    __syncthreads();
    for (int kt = 0; kt < 4; ++kt) {
      const int cur = kt & 1;
      if (kt < 3) GM_STAGE(cur ^ 1, kt + 1);
#pragma unroll
      for (int kk = 0; kk < 2; ++kk) {
        int kb = kk * 64 + ((lane >> 4) << 4);
        bf16x8 af[4], bfr[4];
#pragma unroll
        for (int mf = 0; mf < 4; ++mf) {
          int row = wr * 64 + mf * 16 + (lane & 15);
          af[mf] = *(const bf16x8*)(As + cur * 16384 + (((row * 128 + kb)) ^ ((row & 7) << 4)));
        }
#pragma unroll
        for (int nf = 0; nf < 4; ++nf) {
          int nl = wc * 64 + nf * 16 + (lane & 15);
          bfr[nf] = *(const bf16x8*)(Bs + cur * 16384 + (((nl * 128 + kb)) ^ ((nl & 7) << 4)));
        }
#pragma unroll
        for (int mf = 0; mf < 4; ++mf)
#pragma unroll
          for (int nf = 0; nf < 4; ++nf)
            acc[mf][nf] = __builtin_amdgcn_mfma_f32_16x16x32_bf16(af[mf], bfr[nf], acc[mf][nf], 0, 0, 0);
      }
      __syncthreads();
    }
    char* ep = smem;
#pragma unroll
    for (int nf = 0; nf < 4; ++nf) {
      int col = wc * 64 + nf * 16 + (lane & 15);
      float bg = b_gh[nb * 128 + col];
#pragma unroll
      for (int mf = 0; mf < 4; ++mf)
#pragma unroll
        for (int reg = 0; reg < 4; ++reg) {
          int row = wr * 64 + mf * 16 + ((lane >> 4) << 2) + reg;
          int cph = ((col >> 3) ^ (((row >> 2) & 3) << 2));
          *(bf16*)(ep + row * 256 + (cph << 4) + (col & 7) * 2) =
              (bf16)__expf(-fmaxf(acc[mf][nf][reg] + bg, 0.f));
        }
    }
    __syncthreads();
#pragma unroll
    for (int p = 0; p < 8; ++p) {
      int idx = p * 256 + tid;
      int row = idx >> 4, c = idx & 15;
      int cph = c ^ (((row >> 2) & 3) << 2);
      bf16x8 v = *(const bf16x8*)(ep + row * 256 + (cph << 4));
      __builtin_nontemporal_store(v, (bf16x8*)(GH + (size_t)(mb * 128 + row) * 1024 + nb * 128 + c * 8));
    }
  }
}

// ---------------------------------------------------------------------------
// step: single-plane i8 h-GEMM (R16 verbatim)
// ---------------------------------------------------------------------------
__global__ __launch_bounds__(512, 4) void step_kernel(
    const char* __restrict__ hbs, const bf16* __restrict__ hf,
    const char* __restrict__ WcH3, const float* __restrict__ bias4,
    const bf16* __restrict__ gi, const bf16* __restrict__ gh_next, int is_last,
    bf16* __restrict__ hf_next, char* __restrict__ hbs_next) {
  __shared__ char smem[49152];   // A [2][8192] @0, B [2][16384] @16384
  int tid = threadIdx.x, lane = tid & 63, wid = tid >> 6;
  int wr = wid >> 1, wc = wid & 1;
  int wg = ((blockIdx.x & 7) << 6) + (blockIdx.x >> 3);
  int mb = wg & 15, nb = wg >> 4;

  const char* aA = hbs + (size_t)(mb * 64 + (tid >> 3)) * 1024 + (tid & 7) * 16;
  const char* aB = WcH3 + (size_t)nb * 131072 + (tid >> 3) * 128 + (tid & 7) * 16;

  int j = nb * 32 + wc * 16 + (lane & 15);
  bf16  grv[4], gzv[4], gnv[4], ghv[4], hfv[4];
#pragma unroll
  for (int reg = 0; reg < 4; ++reg) {
    int brow = mb * 64 + wr * 16 + ((lane >> 4) << 2) + reg;
    size_t hb_ = (size_t)brow * 1024 + j;
    grv[reg] = gi[hb_];
    gzv[reg] = gi[1048576 + hb_];
    gnv[reg] = gi[2097152 + hb_];
    ghv[reg] = gh_next[hb_];
    hfv[reg] = hf[hb_];
  }

  i32x4 acc[4];
#pragma unroll
  for (int b = 0; b < 4; ++b)
#pragma unroll
    for (int q = 0; q < 4; ++q) acc[b][q] = 0;

#define ST_STAGE(buf, kt)                                                            \
  do {                                                                               \
    GLL16(aA + (kt) * 128,            smem + (buf) * 8192 + wid * 1024);             \
    GLL16(aB + (kt) * 16384,          smem + 16384 + (buf) * 16384 + wid * 1024);    \
    GLL16(aB + (kt) * 16384 + 8192,   smem + 16384 + (buf) * 16384 + 8192 + wid * 1024); \
  } while (0)

  ST_STAGE(0, 0);
  __syncthreads();
  for (int kt = 0; kt < 8; ++kt) {
    const int cur = kt & 1;
    if (kt < 7) ST_STAGE(cur ^ 1, kt + 1);
    const char* Ab = smem + cur * 8192;
    const char* Bb = smem + 16384 + cur * 16384;
#pragma unroll
    for (int kk = 0; kk < 2; ++kk) {
      int kb = kk * 64 + ((lane >> 4) << 4);
      int row = wr * 16 + (lane & 15);
      i32x4 af = *(const i32x4*)(Ab + ((row * 128 + (kb ^ ((row & 7) << 4)))));
      i32x4 bfr[4];
#pragma unroll
      for (int g = 0; g < 4; ++g) {
        int nl = g * 32 + wc * 16 + (lane & 15);
        bfr[g] = *(const i32x4*)(Bb + ((nl * 128 + (kb ^ ((nl & 7) << 4)))));
      }
#pragma unroll
      for (int g = 0; g < 4; ++g)
        acc[g] = __builtin_amdgcn_mfma_i32_16x16x64_i8(af, bfr[g], acc[g], 0, 0, 0);
    }
    __syncthreads();
  }

  const float ISC_RZ = 3.814697265625e-06f;    // 1/(128*2048)
  const float ISC_N  = 1.9073486328125e-06f;   // 1/(128*4096)
  float br = bias4[j], bz = bias4[1024 + j], bn = bias4[2048 + j], bh = bias4[3072 + j];
#pragma unroll
  for (int reg = 0; reg < 4; ++reg) {
    int brow = mb * 64 + wr * 16 + ((lane >> 4) << 2) + reg;
    float pr  = (float)acc[0][reg] * ISC_RZ + (float)grv[reg] + br;
    float pz  = (float)acc[1][reg] * ISC_RZ + (float)gzv[reg] + bz;
    float pin = (float)acc[2][reg] * ISC_N  + (float)gnv[reg] + bn;
    float phn = (float)acc[3][reg] * ISC_N  + bh;
    float r = sigm(pr), z = sigm(pz);
    float nn = tanh_fast(pin + r * phn);
    float hnew = (1.f - z) * nn + z * (float)hfv[reg];
    float gam = is_last ? 1.f : (float)ghv[reg];
    float hd = hnew * gam;
    hf_next[(size_t)brow * 1024 + j] = (bf16)hd;
    int hi8 = __float2int_rn(hd * 128.f);
    hi8 = hi8 > 127 ? 127 : (hi8 < -127 ? -127 : hi8);
    hbs_next[(size_t)brow * 1024 + (j ^ ((brow & 7) << 4))] = (char)hi8;
  }
}

// ---------------------------------------------------------------------------
// classifier + softmax (bf16 h)
// ---------------------------------------------------------------------------
__global__ void cls_kernel(const bf16* __restrict__ h, const float* __restrict__ w_cls,
                           const float* __restrict__ b_cls, float* __restrict__ out) {
  int wid = threadIdx.x >> 6, lane = threadIdx.x & 63;
  int b = blockIdx.x * 4 + wid;
  const bf16* hb = h + (size_t)b * 1024;
  float a0 = 0.f, a1 = 0.f;
#pragma unroll
  for (int e = 0; e < 16; ++e) {
    int i = e * 64 + lane;
    float hv = (float)hb[i];
    a0 += hv * w_cls[i];
    a1 += hv * w_cls[1024 + i];
  }
  for (int off = 32; off; off >>= 1) {
    a0 += __shfl_down(a0, off);
    a1 += __shfl_down(a1, off);
  }
  if (lane == 0) {
    float l0 = a0 + b_cls[0], l1 = a1 + b_cls[1];
    float mx = fmaxf(l0, l1);
    float e0 = __expf(l0 - mx), e1 = __expf(l1 - mx);
    float s = e0 + e1;
    out[b * 2]     = e0 / s;
    out[b * 2 + 1] = e1 / s;
  }
}

// ---------------------------------------------------------------------------
extern "C" void kernel_launch(void* const* d_in, const int* in_sizes, int n_in,
                              void* d_out, int out_size, void* d_ws, size_t ws_size,
                              hipStream_t stream) {
  const float* X     = (const float*)d_in[0];
  const float* Msk   = (const float*)d_in[1];
  const float* D     = (const float*)d_in[2];
  const float* Mean  = (const float*)d_in[3];
  const float* L     = (const float*)d_in[4];
  const float* w_gh  = (const float*)d_in[5];
  const float* b_gh  = (const float*)d_in[6];
  const float* w_gx  = (const float*)d_in[7];
  const float* b_gx  = (const float*)d_in[8];
  const float* w_ih  = (const float*)d_in[9];
  const float* w_hh  = (const float*)d_in[10];
  const float* b_ih  = (const float*)d_in[11];
  const float* b_hh  = (const float*)d_in[12];
  const float* w_cls = (const float*)d_in[13];
  const float* b_cls = (const float*)d_in[14];

  char* w = (char*)d_ws;
  bf16*  XRp[2]  = {(bf16*)(w), (bf16*)(w + 16777216)};
  bf16*  Dbp[2]  = {(bf16*)(w + 33554432), (bf16*)(w + 42467328)};
  bf16*  GH      = (bf16*)(w + 51380224);
  bf16*  WcX3    = (bf16*)(w + 87031808);
  char*  WcH3    = (char*)(w + 90177536);
  bf16*  Wgs     = (bf16*)(w + 94371840);
  float* bias4   = (float*)(w + 94896128);
  bf16*  hfp[2]  = {(bf16*)(w + 94912512), (bf16*)(w + 97009664)};
  char*  hbp[2]  = {(char*)(w + 99106816), (char*)(w + 100155392)};
  bf16*  Gi      = (bf16*)(w + 101203968);

  hipMemsetAsync(hfp[0], 0, 2097152, stream);
  hipMemsetAsync(hbp[0], 0, 1048576, stream);
  wprep_kernel<<<23568, 256, 0, stream>>>(w_ih, w_hh, b_ih, b_hh, w_gh, WcH3, WcX3, Wgs, bias4);

  // chunk 0 prep (standalone, full occupancy)
  prep_kernel<<<17 * 1024, 256, 0, stream>>>(X, Msk, D, Mean, L, w_gx, b_gx, XRp[0], Dbp[0], 0, 17);

  int t = 0;
  for (int c = 0; c < 4; ++c) {
    int pr = c & 1, pn = pr ^ 1;
    int nsl  = (c < 3) ? 17 : 16;
    int npsl = (c < 3) ? ((c + 1 < 3) ? 17 : 16) : 0;
    int gxblocks = 3072, gmblocks = nsl * 64;
    int pp = (npsl > 0) ? 1024 : 0;
    int grid = gxblocks + gmblocks + pp;
    combo_kernel<<<grid, 256, 0, stream>>>(
        XRp[pr], WcX3, Gi, gxblocks,
        Dbp[pr], Wgs, b_gh, GH, gmblocks,
        X, Msk, D, Mean, L, w_gx, b_gx, XRp[pn], Dbp[pn], c + 1, npsl, pp);
    for (int tl = 0; tl < 16; ++tl, ++t) {
      int cur = t & 1, nxt = cur ^ 1;
      step_kernel<<<512, 512, 0, stream>>>(
          hbp[cur], hfp[cur], WcH3, bias4,
          Gi + (size_t)tl * 3145728, GH + (size_t)(tl + 1) * 1048576,
          (t == 63) ? 1 : 0, hfp[nxt], hbp[nxt]);
    }
  }
  cls_kernel<<<256, 256, 0, stream>>>(hfp[0], w_cls, b_cls, (float*)d_out);
}

// Round 19
// 1125.089 us; speedup vs baseline: 1.0890x; 1.0890x over previous
//
#include <hip/hip_runtime.h>

using bf16   = __bf16;
using bf16x8 = __bf16 __attribute__((ext_vector_type(8)));
using f32x4  = float  __attribute__((ext_vector_type(4)));
using i32x4  = int    __attribute__((ext_vector_type(4)));

// B=1024, T=64, F=256, H=1024, C=2
// ws layout: R16's. WcH3 i8, hb i8 single-plane (the ONLY h state now),
// hfF bf16 written only at t=63 for the classifier.

__device__ __forceinline__ float sigm(float x) { return 1.f / (1.f + __expf(-x)); }
__device__ __forceinline__ float tanh_fast(float x) {
  float e = __expf(2.f * x);
  return 1.f - 2.f / (e + 1.f);
}

#define GLL16(gsrc, ldst)                                                              \
  __builtin_amdgcn_global_load_lds((const __attribute__((address_space(1))) void*)(gsrc), \
                                   (__attribute__((address_space(3))) void*)(ldst), 16, 0, 0)

// ---------------------------------------------------------------------------
// prep: pre-swizzled XRs ([xr|m], f XOR (b&7)<<3) and Dbfs   (R16 verbatim)
// ---------------------------------------------------------------------------
__global__ void prep_kernel(const float* __restrict__ X, const float* __restrict__ Msk,
                            const float* __restrict__ D, const float* __restrict__ Mean,
                            const float* __restrict__ L, const float* __restrict__ w_gx,
                            const float* __restrict__ b_gx,
                            bf16* __restrict__ XRs, bf16* __restrict__ Dbfs,
                            int c, int nsl) {
  int i = blockIdx.x * 256 + threadIdx.x;
  if (i >= (nsl << 18)) return;
  int f = i & 255, b = (i >> 8) & 1023, tl = i >> 18;
  int t = c * 16 + tl;
  size_t g = ((size_t)b << 14) + ((size_t)t << 8) + f;
  float d = D[g];
  int fs = f ^ ((b & 7) << 3);
  int row = tl * 1024 + b;
  Dbfs[(size_t)row * 256 + fs] = (bf16)d;
  float gx = __expf(-fmaxf(d * w_gx[f] + b_gx[f], 0.f));
  float xh = gx * L[g] + (1.f - gx) * Mean[(size_t)b * 256 + f];
  float m  = Msk[g];
  float xr = m * X[g] + (1.f - m) * xh;
  if (tl < 16) {
    size_t xo = (size_t)row * 512;
    XRs[xo + fs]       = (bf16)xr;
    XRs[xo + 256 + fs] = (bf16)m;
  }
}

// ---------------------------------------------------------------------------
// wprep: WcH3 i8 with per-gate scales (R16 verbatim)
// ---------------------------------------------------------------------------
__global__ void wprep_kernel(const float* __restrict__ w_ih, const float* __restrict__ w_hh,
                             const float* __restrict__ b_ih, const float* __restrict__ b_hh,
                             const float* __restrict__ w_gh,
                             char* __restrict__ WcH3, bf16* __restrict__ WcX3,
                             bf16* __restrict__ Wgs, float* __restrict__ bias4) {
  int i = blockIdx.x * 256 + threadIdx.x;
  if (i < 4194304) {                       // WcH3 i8: [nb32][kt8][nl128][cc8][e16]
    int nb = i >> 17;
    int rem = i & 131071;
    int kt = rem >> 14;
    int r2 = rem & 16383;
    int nl = r2 >> 7, bb = r2 & 127;
    int cc = bb >> 4, e = bb & 15;
    int gg = nl >> 5, j = nb * 32 + (nl & 31);
    int k = kt * 128 + ((cc ^ (nl & 7)) << 4) + e;
    float v;
    if (gg == 3) v = w_hh[(size_t)(2048 + j) * 1024 + k];
    else {
      int rr = gg * 1024 + j;
      v = w_ih[(size_t)rr * 1536 + 256 + k];
      if (gg < 2) v += w_hh[(size_t)rr * 1024 + k];
    }
    float sc = (gg >= 2) ? 4096.f : 2048.f;
    int wq = __float2int_rn(v * sc);
    wq = wq > 127 ? 127 : (wq < -127 ? -127 : wq);
    WcH3[i] = (char)wq;
  } else if (i < 5767168) {                // WcX3: [nb24][kt8][nl128][c8][e8], n=g*1024+j
    int q = i - 4194304;
    int blk = q >> 13;
    int nb = blk >> 3, kt = blk & 7;
    int r = q & 8191;
    int nl = r >> 6, cc = (r >> 3) & 7, e = r & 7;
    int gg = nb >> 3;                       // 0..2
    int j  = (nb & 7) * 128 + nl;
    int rr = gg * 1024 + j;
    int k = kt * 64 + ((cc ^ (nl & 7)) << 3) + e;
    float v = (k < 256) ? w_ih[(size_t)rr * 1536 + k]
                        : w_ih[(size_t)rr * 1536 + 1280 + (k - 256)];
    WcX3[q] = (bf16)v;
  } else if (i < 6029312) {                // Wgs
    int q = i - 5767168;
    int blk = q >> 13;
    int nb = blk >> 2, kt = blk & 3;
    int r = q & 8191;
    int nl = r >> 6, cc = (r >> 3) & 7, e = r & 7;
    int n = nb * 128 + nl;
    int k = kt * 64 + ((cc ^ (nl & 7)) << 3) + e;
    Wgs[q] = (bf16)w_gh[(size_t)n * 256 + k];
  } else if (i < 6033408) {                // bias4
    int q = i - 6029312;
    int gg = q >> 10, j = q & 1023;
    float v;
    if (gg == 0)      v = b_ih[j] + b_hh[j];
    else if (gg == 1) v = b_ih[1024 + j] + b_hh[1024 + j];
    else if (gg == 2) v = b_ih[2048 + j];
    else              v = b_hh[2048 + j];
    bias4[q] = v;
  }
}

// ---------------------------------------------------------------------------
// combo: gix + gammah roles, NT output stores (R16 verbatim)
// ---------------------------------------------------------------------------
__global__ __launch_bounds__(256) void combo_kernel(
    const bf16* __restrict__ XRs, const bf16* __restrict__ WcX3,
    bf16* __restrict__ Gi, int gxblocks,
    const bf16* __restrict__ Dbfs, const bf16* __restrict__ Wgs,
    const float* __restrict__ b_gh, bf16* __restrict__ GH, int gmblocks) {
  __shared__ char smem[65536];
  char* As = smem;
  char* Bs = smem + 32768;
  int bid = blockIdx.x;
  int tid = threadIdx.x, lane = tid & 63, wid = tid >> 6;
  int wr = wid >> 1, wc = wid & 1;

  if (bid < gxblocks) {
    // ------------------------- gix role -------------------------
    int cpx = gxblocks >> 3;
    int wg = (bid & 7) * cpx + (bid >> 3);
    int nb = wg % 24, mb = wg / 24;

    const bf16* aA = XRs + ((size_t)(mb * 128 + wid * 8 + (lane >> 3))) * 512 + (lane & 7) * 8;
    const bf16* aB = WcX3 + (size_t)nb * 8 * 8192 + wid * 512 + lane * 8;

    f32x4 acc[4][4];
#pragma unroll
    for (int a = 0; a < 4; ++a)
#pragma unroll
      for (int b = 0; b < 4; ++b)
#pragma unroll
        for (int q = 0; q < 4; ++q) acc[a][b][q] = 0.f;

#define GX_STAGE(buf, kt)                                                         \
  do {                                                                            \
    _Pragma("unroll")                                                             \
    for (int q = 0; q < 4; ++q)                                                   \
      GLL16(aA + q * (32 * 512) + (kt) * 64, As + (buf) * 16384 + (q * 4 + wid) * 1024); \
    _Pragma("unroll")                                                             \
    for (int q = 0; q < 4; ++q)                                                   \
      GLL16(aB + (size_t)(kt) * 8192 + q * 2048, Bs + (buf) * 16384 + (q * 4 + wid) * 1024); \
  } while (0)

    GX_STAGE(0, 0);
    __syncthreads();
    for (int kt = 0; kt < 8; ++kt) {
      const int cur = kt & 1;
      if (kt < 7) GX_STAGE(cur ^ 1, kt + 1);
#pragma unroll
      for (int kk = 0; kk < 2; ++kk) {
        int kb = kk * 64 + ((lane >> 4) << 4);
        bf16x8 af[4], bfr[4];
#pragma unroll
        for (int mf = 0; mf < 4; ++mf) {
          int row = wr * 64 + mf * 16 + (lane & 15);
          af[mf] = *(const bf16x8*)(As + cur * 16384 + (((row * 128 + kb)) ^ ((row & 7) << 4)));
        }
#pragma unroll
        for (int nf = 0; nf < 4; ++nf) {
          int nl = wc * 64 + nf * 16 + (lane & 15);
          bfr[nf] = *(const bf16x8*)(Bs + cur * 16384 + (((nl * 128 + kb)) ^ ((nl & 7) << 4)));
        }
#pragma unroll
        for (int mf = 0; mf < 4; ++mf)
#pragma unroll
          for (int nf = 0; nf < 4; ++nf)
            acc[mf][nf] = __builtin_amdgcn_mfma_f32_16x16x32_bf16(af[mf], bfr[nf], acc[mf][nf], 0, 0, 0);
      }
      __syncthreads();
    }
    char* ep = smem;
#pragma unroll
    for (int nf = 0; nf < 4; ++nf) {
      int col = wc * 64 + nf * 16 + (lane & 15);
#pragma unroll
      for (int mf = 0; mf < 4; ++mf)
#pragma unroll
        for (int reg = 0; reg < 4; ++reg) {
          int row = wr * 64 + mf * 16 + ((lane >> 4) << 2) + reg;
          int cph = ((col >> 3) ^ (((row >> 2) & 3) << 2));
          *(bf16*)(ep + row * 256 + (cph << 4) + (col & 7) * 2) = (bf16)acc[mf][nf][reg];
        }
    }
    __syncthreads();
    {
      int sl = mb >> 3, mbl = mb & 7;
      bf16* plane = Gi + (size_t)sl * 3145728 + (size_t)(nb >> 3) * 1048576 + (nb & 7) * 128;
#pragma unroll
      for (int p = 0; p < 8; ++p) {
        int idx = p * 256 + tid;
        int row = idx >> 4, c = idx & 15;
        int cph = c ^ (((row >> 2) & 3) << 2);
        bf16x8 v = *(const bf16x8*)(ep + row * 256 + (cph << 4));
        __builtin_nontemporal_store(v, (bf16x8*)(plane + (size_t)(mbl * 128 + row) * 1024 + c * 8));
      }
    }
    return;
  }

  // ------------------------- gammah role -------------------------
  {
    int lbid = bid - gxblocks;
    int cpx = gmblocks >> 3;
    int wg = (lbid & 7) * cpx + (lbid >> 3);
    int nb = wg & 7, mb = wg >> 3;

    const bf16* aA = Dbfs + ((size_t)(mb * 128 + wid * 8 + (lane >> 3))) * 256 + (lane & 7) * 8;
    const bf16* aB = Wgs + (size_t)nb * 4 * 8192 + wid * 512 + lane * 8;

    f32x4 acc[4][4];
#pragma unroll
    for (int a = 0; a < 4; ++a)
#pragma unroll
      for (int b = 0; b < 4; ++b)
#pragma unroll
        for (int q = 0; q < 4; ++q) acc[a][b][q] = 0.f;

#define GM_STAGE(buf, kt)                                                         \
  do {                                                                            \
    _Pragma("unroll")                                                             \
    for (int q = 0; q < 4; ++q)                                                   \
      GLL16(aA + q * (32 * 256) + (kt) * 64, As + (buf) * 16384 + (q * 4 + wid) * 1024); \
    _Pragma("unroll")                                                             \
    for (int q = 0; q < 4; ++q)                                                   \
      GLL16(aB + (size_t)(kt) * 8192 + q * 2048, Bs + (buf) * 16384 + (q * 4 + wid) * 1024); \
  } while (0)

    GM_STAGE(0, 0);
    __syncthreads();
    for (int kt = 0; kt < 4; ++kt) {
      const int cur = kt & 1;
      if (kt < 3) GM_STAGE(cur ^ 1, kt + 1);
#pragma unroll
      for (int kk = 0; kk < 2; ++kk) {
        int kb = kk * 64 + ((lane >> 4) << 4);
        bf16x8 af[4], bfr[4];
#pragma unroll
        for (int mf = 0; mf < 4; ++mf) {
          int row = wr * 64 + mf * 16 + (lane & 15);
          af[mf] = *(const bf16x8*)(As + cur * 16384 + (((row * 128 + kb)) ^ ((row & 7) << 4)));
        }
#pragma unroll
        for (int nf = 0; nf < 4; ++nf) {
          int nl = wc * 64 + nf * 16 + (lane & 15);
          bfr[nf] = *(const bf16x8*)(Bs + cur * 16384 + (((nl * 128 + kb)) ^ ((nl & 7) << 4)));
        }
#pragma unroll
        for (int mf = 0; mf < 4; ++mf)
#pragma unroll
          for (int nf = 0; nf < 4; ++nf)
            acc[mf][nf] = __builtin_amdgcn_mfma_f32_16x16x32_bf16(af[mf], bfr[nf], acc[mf][nf], 0, 0, 0);
      }
      __syncthreads();
    }
    char* ep = smem;
#pragma unroll
    for (int nf = 0; nf < 4; ++nf) {
      int col = wc * 64 + nf * 16 + (lane & 15);
      float bg = b_gh[nb * 128 + col];
#pragma unroll
      for (int mf = 0; mf < 4; ++mf)
#pragma unroll
        for (int reg = 0; reg < 4; ++reg) {
          int row = wr * 64 + mf * 16 + ((lane >> 4) << 2) + reg;
          int cph = ((col >> 3) ^ (((row >> 2) & 3) << 2));
          *(bf16*)(ep + row * 256 + (cph << 4) + (col & 7) * 2) =
              (bf16)__expf(-fmaxf(acc[mf][nf][reg] + bg, 0.f));
        }
    }
    __syncthreads();
#pragma unroll
    for (int p = 0; p < 8; ++p) {
      int idx = p * 256 + tid;
      int row = idx >> 4, c = idx & 15;
      int cph = c ^ (((row >> 2) & 3) << 2);
      bf16x8 v = *(const bf16x8*)(ep + row * 256 + (cph << 4));
      __builtin_nontemporal_store(v, (bf16x8*)(GH + (size_t)(mb * 128 + row) * 1024 + nb * 128 + c * 8));
    }
  }
}

// ---------------------------------------------------------------------------
// step: single-plane i8 h-GEMM; hold read from the LDS A-tile (no hf buffer).
// hfF written only when is_last (for the classifier).
// ---------------------------------------------------------------------------
__global__ __launch_bounds__(512, 4) void step_kernel(
    const char* __restrict__ hbs,
    const char* __restrict__ WcH3, const float* __restrict__ bias4,
    const bf16* __restrict__ gi, const bf16* __restrict__ gh_next, int is_last,
    bf16* __restrict__ hfF, char* __restrict__ hbs_next) {
  __shared__ char smem[49152];   // A [2][8192] @0, B [2][16384] @16384
  int tid = threadIdx.x, lane = tid & 63, wid = tid >> 6;
  int wr = wid >> 1, wc = wid & 1;
  int wg = ((blockIdx.x & 7) << 6) + (blockIdx.x >> 3);
  int mb = wg & 15, nb = wg >> 4;

  const char* aA = hbs + (size_t)(mb * 64 + (tid >> 3)) * 1024 + (tid & 7) * 16;
  const char* aB = WcH3 + (size_t)nb * 131072 + (tid >> 3) * 128 + (tid & 7) * 16;

  int jc = wc * 16 + (lane & 15);
  int j = nb * 32 + jc;
  bf16  grv[4], gzv[4], gnv[4], ghv[4];
#pragma unroll
  for (int reg = 0; reg < 4; ++reg) {
    int brow = mb * 64 + wr * 16 + ((lane >> 4) << 2) + reg;
    size_t hb_ = (size_t)brow * 1024 + j;
    grv[reg] = gi[hb_];
    gzv[reg] = gi[1048576 + hb_];
    gnv[reg] = gi[2097152 + hb_];
    ghv[reg] = gh_next[hb_];
  }

  i32x4 acc[4];
#pragma unroll
  for (int b = 0; b < 4; ++b)
#pragma unroll
    for (int q = 0; q < 4; ++q) acc[b][q] = 0;
  char hqv[4];

#define ST_STAGE(buf, kt)                                                            \
  do {                                                                               \
    GLL16(aA + (kt) * 128,            smem + (buf) * 8192 + wid * 1024);             \
    GLL16(aB + (kt) * 16384,          smem + 16384 + (buf) * 16384 + wid * 1024);    \
    GLL16(aB + (kt) * 16384 + 8192,   smem + 16384 + (buf) * 16384 + 8192 + wid * 1024); \
  } while (0)

  ST_STAGE(0, 0);
  __syncthreads();
  const int hkt = nb >> 2;    // K-slice containing h columns [nb*32, nb*32+32)
  for (int kt = 0; kt < 8; ++kt) {
    const int cur = kt & 1;
    if (kt < 7) ST_STAGE(cur ^ 1, kt + 1);
    const char* Ab = smem + cur * 8192;
    const char* Bb = smem + 16384 + cur * 16384;
#pragma unroll
    for (int kk = 0; kk < 2; ++kk) {
      int kb = kk * 64 + ((lane >> 4) << 4);
      int row = wr * 16 + (lane & 15);
      i32x4 af = *(const i32x4*)(Ab + ((row * 128 + (kb ^ ((row & 7) << 4)))));
      i32x4 bfr[4];
#pragma unroll
      for (int g = 0; g < 4; ++g) {
        int nl = g * 32 + wc * 16 + (lane & 15);
        bfr[g] = *(const i32x4*)(Bb + ((nl * 128 + (kb ^ ((nl & 7) << 4)))));
      }
#pragma unroll
      for (int g = 0; g < 4; ++g)
        acc[g] = __builtin_amdgcn_mfma_i32_16x16x64_i8(af, bfr[g], acc[g], 0, 0, 0);
    }
    if (kt == hkt) {
      // hold = decayed h, read from the A-tile already in LDS (i8 x128).
      // logical col (nb*32+jc) within slice: byte (nb&3)*32+jc, XOR row swizzle.
#pragma unroll
      for (int reg = 0; reg < 4; ++reg) {
        int lr = wr * 16 + ((lane >> 4) << 2) + reg;
        hqv[reg] = *(const char*)(Ab + lr * 128 + ((((nb & 3) * 32 + jc)) ^ ((lr & 7) << 4)));
      }
    }
    __syncthreads();
  }

  const float ISC_RZ = 3.814697265625e-06f;    // 1/(128*2048)
  const float ISC_N  = 1.9073486328125e-06f;   // 1/(128*4096)
  float br = bias4[j], bz = bias4[1024 + j], bn = bias4[2048 + j], bh = bias4[3072 + j];
#pragma unroll
  for (int reg = 0; reg < 4; ++reg) {
    int brow = mb * 64 + wr * 16 + ((lane >> 4) << 2) + reg;
    float pr  = (float)acc[0][reg] * ISC_RZ + (float)grv[reg] + br;
    float pz  = (float)acc[1][reg] * ISC_RZ + (float)gzv[reg] + bz;
    float pin = (float)acc[2][reg] * ISC_N  + (float)gnv[reg] + bn;
    float phn = (float)acc[3][reg] * ISC_N  + bh;
    float r = sigm(pr), z = sigm(pz);
    float nn = tanh_fast(pin + r * phn);
    float hold = (float)hqv[reg] * 0.0078125f;   // hq/128
    float hnew = (1.f - z) * nn + z * hold;
    float gam = is_last ? 1.f : (float)ghv[reg];
    float hd = hnew * gam;
    if (is_last) hfF[(size_t)brow * 1024 + j] = (bf16)hd;
    int hi8 = __float2int_rn(hd * 128.f);
    hi8 = hi8 > 127 ? 127 : (hi8 < -127 ? -127 : hi8);
    hbs_next[(size_t)brow * 1024 + (j ^ ((brow & 7) << 4))] = (char)hi8;
  }
}

// ---------------------------------------------------------------------------
// classifier + softmax (bf16 h)
// ---------------------------------------------------------------------------
__global__ void cls_kernel(const bf16* __restrict__ h, const float* __restrict__ w_cls,
                           const float* __restrict__ b_cls, float* __restrict__ out) {
  int wid = threadIdx.x >> 6, lane = threadIdx.x & 63;
  int b = blockIdx.x * 4 + wid;
  const bf16* hb = h + (size_t)b * 1024;
  float a0 = 0.f, a1 = 0.f;
#pragma unroll
  for (int e = 0; e < 16; ++e) {
    int i = e * 64 + lane;
    float hv = (float)hb[i];
    a0 += hv * w_cls[i];
    a1 += hv * w_cls[1024 + i];
  }
  for (int off = 32; off; off >>= 1) {
    a0 += __shfl_down(a0, off);
    a1 += __shfl_down(a1, off);
  }
  if (lane == 0) {
    float l0 = a0 + b_cls[0], l1 = a1 + b_cls[1];
    float mx = fmaxf(l0, l1);
    float e0 = __expf(l0 - mx), e1 = __expf(l1 - mx);
    float s = e0 + e1;
    out[b * 2]     = e0 / s;
    out[b * 2 + 1] = e1 / s;
  }
}

// ---------------------------------------------------------------------------
extern "C" void kernel_launch(void* const* d_in, const int* in_sizes, int n_in,
                              void* d_out, int out_size, void* d_ws, size_t ws_size,
                              hipStream_t stream) {
  const float* X     = (const float*)d_in[0];
  const float* Msk   = (const float*)d_in[1];
  const float* D     = (const float*)d_in[2];
  const float* Mean  = (const float*)d_in[3];
  const float* L     = (const float*)d_in[4];
  const float* w_gh  = (const float*)d_in[5];
  const float* b_gh  = (const float*)d_in[6];
  const float* w_gx  = (const float*)d_in[7];
  const float* b_gx  = (const float*)d_in[8];
  const float* w_ih  = (const float*)d_in[9];
  const float* w_hh  = (const float*)d_in[10];
  const float* b_ih  = (const float*)d_in[11];
  const float* b_hh  = (const float*)d_in[12];
  const float* w_cls = (const float*)d_in[13];
  const float* b_cls = (const float*)d_in[14];

  char* w = (char*)d_ws;
  bf16*  XRs   = (bf16*)(w);
  bf16*  Dbfs  = (bf16*)(w + 16777216);
  bf16*  GH    = (bf16*)(w + 25690112);
  bf16*  WcX3  = (bf16*)(w + 61341696);
  char*  WcH3  = (char*)(w + 65536000);
  bf16*  Wgs   = (bf16*)(w + 73924608);
  float* bias4 = (float*)(w + 74448896);
  bf16*  hfF   = (bf16*)(w + 74465280);
  char*  hb0   = (char*)(w + 82853888);
  char*  hb1   = (char*)(w + 84951040);
  bf16*  Gi    = (bf16*)(w + 87048192);

  char* hbp[2] = {hb0, hb1};

  hipMemsetAsync(hb0, 0, 1048576, stream);
  wprep_kernel<<<23568, 256, 0, stream>>>(w_ih, w_hh, b_ih, b_hh, w_gh, WcH3, WcX3, Wgs, bias4);

  int t = 0;
  for (int c = 0; c < 4; ++c) {
    int nsl = (c < 3) ? 17 : 16;
    prep_kernel<<<nsl * 1024, 256, 0, stream>>>(X, Msk, D, Mean, L, w_gx, b_gx, XRs, Dbfs, c, nsl);
    combo_kernel<<<3072 + nsl * 64, 256, 0, stream>>>(
        XRs, WcX3, Gi, 3072, Dbfs, Wgs, b_gh, GH, nsl * 64);
    for (int tl = 0; tl < 16; ++tl, ++t) {
      int cur = t & 1, nxt = cur ^ 1;
      step_kernel<<<512, 512, 0, stream>>>(
          hbp[cur], WcH3, bias4,
          Gi + (size_t)tl * 3145728, GH + (size_t)(tl + 1) * 1048576,
          (t == 63) ? 1 : 0, hfF, hbp[nxt]);
    }
  }
  cls_kernel<<<256, 256, 0, stream>>>(hfF, w_cls, b_cls, (float*)d_out);
}